// Round 4
// baseline (464.781 us; speedup 1.0000x reference)
//
#include <hip/hip_runtime.h>
#include <hip/hip_bf16.h>
#include <stdint.h>

#define IN_DIM   128
#define OUT_DIM  64
#define NCH      8
#define N_REL    500
#define BN_EPS   1e-5f

// ---------------------------------------------------------------------------
// Wave-uniform dual-dtype float load: f32 ? fp32[i] : bf16[i]
// ---------------------------------------------------------------------------
__device__ __forceinline__ float ldf(const void* p, bool f32, long i) {
    return f32 ? ((const float*)p)[i]
               : __bfloat162float(((const __hip_bfloat16*)p)[i]);
}

// ---------------------------------------------------------------------------
// Kernel 0: detect dtypes on-device.
//   flags[0] = 1 if triple is int64 (value-range test on first 1024 edges)
//   flags[1] = 1 if floats are fp32 (low-half-as-bf16 exponent test on input)
// Probe reads are in-bounds under every interpretation.
// ---------------------------------------------------------------------------
__global__ __launch_bounds__(256) void k_detect(
    const void* __restrict__ triple, int probeT, int N,
    const unsigned int* __restrict__ finput, int probeW,
    int* __restrict__ flags)
{
    __shared__ int bad64, bigexp;
    if (threadIdx.x == 0) { bad64 = 0; bigexp = 0; }
    __syncthreads();
    const int64_t* t64 = (const int64_t*)triple;
    int lb = 0;
    for (int j = threadIdx.x; j < probeT; j += 256) {
        int64_t h = t64[3 * j], r = t64[3 * j + 1], t = t64[3 * j + 2];
        if (h < 0 || h >= N || r < 0 || r >= N_REL || t < 0 || t >= N) lb = 1;
    }
    if (lb) atomicOr(&bad64, 1);
    int le = 0;
    for (int i = threadIdx.x; i < probeW; i += 256) {
        unsigned int e = (finput[i] >> 7) & 0xFF;  // exponent of low half viewed as bf16
        if (e >= 134) le = 1;                      // |v|>=64: impossible for N(0,1) bf16 data
    }
    if (le) atomicOr(&bigexp, 1);
    __syncthreads();
    if (threadIdx.x == 0) {
        flags[0] = (bad64 == 0) ? 1 : 0;   // all-valid under int64 view => really int64
        flags[1] = bigexp ? 1 : 0;         // garbage low halves => really fp32
    }
}

// uniform-branch triple loader with clamping (fault-proof)
__device__ __forceinline__ void ld3(const void* tp, bool is64, int j, int N,
                                    int& h, int& r, int& t)
{
    if (is64) {
        const int64_t* p = (const int64_t*)tp;
        h = (int)p[3 * j]; r = (int)p[3 * j + 1]; t = (int)p[3 * j + 2];
    } else {
        const int* p = (const int*)tp;
        h = p[3 * j]; r = p[3 * j + 1]; t = p[3 * j + 2];
    }
    h = min(max(h, 0), N - 1);
    r = min(max(r, 0), N_REL - 1);
    t = min(max(t, 0), N - 1);
}

// ---------------------------------------------------------------------------
// Kernel 1: inp = input @ W   (N,128) x (128,64) -> (N,64) fp32
// Block = 256 = 4 waves; wave computes one row, lane = col. W staged in LDS.
// ---------------------------------------------------------------------------
__global__ __launch_bounds__(256) void k_gemm(
    const void* __restrict__ X, const void* __restrict__ W,
    const int* __restrict__ flags, float* __restrict__ out, int N)
{
    const bool f32 = flags[1] != 0;
    __shared__ float Wl[IN_DIM * OUT_DIM];     // 32 KB
    __shared__ float Xl[4][IN_DIM];
    for (int i = threadIdx.x; i < IN_DIM * OUT_DIM; i += 256)
        Wl[i] = ldf(W, f32, i);
    int row0 = blockIdx.x * 4;
    for (int i = threadIdx.x; i < 4 * IN_DIM; i += 256) {
        int r = i >> 7, k = i & (IN_DIM - 1);
        int rr = row0 + r;
        Xl[r][k] = (rr < N) ? ldf(X, f32, (long)rr * IN_DIM + k) : 0.f;
    }
    __syncthreads();
    int r = threadIdx.x >> 6;
    int c = threadIdx.x & 63;
    float acc = 0.f;
    #pragma unroll
    for (int k = 0; k < IN_DIM; ++k)
        acc = fmaf(Xl[r][k], Wl[k * OUT_DIM + c], acc);
    int rr = row0 + r;
    if (rr < N) out[rr * OUT_DIM + c] = acc;
}

// ordered-uint key for float atomicMax
__device__ __forceinline__ unsigned int f2key(float f) {
    unsigned int b = __float_as_uint(f);
    return b ^ ((b & 0x80000000u) ? 0xFFFFFFFFu : 0x80000000u);
}
__device__ __forceinline__ float key2f(unsigned int k) {
    unsigned int b = k ^ ((k & 0x80000000u) ? 0x80000000u : 0xFFFFFFFFu);
    return __uint_as_float(b);
}

// ---------------------------------------------------------------------------
// Kernel 2: per-edge score e[j] = leaky_relu(fc( relu(bn2(conv(bn1(x)))) ))
// One wave per edge (grid-stride). Lane i = conv output row i (i<62 active).
// BN1/BN2/conv_b folded into per-channel affine (k1c, k0c) around raw stencil.
// ---------------------------------------------------------------------------
__global__ __launch_bounds__(256) void k_score(
    const float* __restrict__ inp, const void* __restrict__ triple,
    const int* __restrict__ flags,
    const void* __restrict__ rel_embed,
    const void* __restrict__ conv_w, const void* __restrict__ conv_b,
    const void* __restrict__ fc_w,
    const void* __restrict__ bn1g, const void* __restrict__ bn1b,
    const void* __restrict__ bn2g, const void* __restrict__ bn2b,
    float* __restrict__ e_out, unsigned int* __restrict__ mkey, int E, int N)
{
    const bool is64  = flags[0] != 0;
    const bool f32   = flags[1] != 0;
    const int lane   = threadIdx.x & 63;
    const int wave   = (blockIdx.x * (blockDim.x >> 6)) + (threadIdx.x >> 6);
    const int nwaves = gridDim.x * (blockDim.x >> 6);

    const float rs  = rsqrtf(1.f + BN_EPS);
    const float s1  = ldf(bn1g, f32, 0) * rs;
    const float be1 = ldf(bn1b, f32, 0);

    float A[NCH][3], Bw[NCH][3], Cw[NCH][3], k0c[NCH], k1c[NCH], fcl[NCH];
    #pragma unroll
    for (int c = 0; c < NCH; ++c) {
        float wsum = 0.f;
        #pragma unroll
        for (int dh = 0; dh < 3; ++dh) {
            float a  = ldf(conv_w, f32, c * 9 + dh * 3 + 0);  // * h[i+dh]
            float b  = ldf(conv_w, f32, c * 9 + dh * 3 + 1);  // * r[i+dh]
            float cc = ldf(conv_w, f32, c * 9 + dh * 3 + 2);  // * t[i+dh]
            A[c][dh] = a; Bw[c][dh] = b; Cw[c][dh] = cc;
            wsum += a + b + cc;
        }
        float s2 = ldf(bn2g, f32, c) * rs;
        float b2 = ldf(bn2b, f32, c);
        k1c[c] = s1 * s2;
        k0c[c] = (be1 * wsum + ldf(conv_b, f32, c)) * s2 + b2;
        fcl[c] = (lane < 62) ? ldf(fc_w, f32, c * 62 + lane) : 0.f;
    }

    for (int j = wave; j < E; j += nwaves) {
        int head, rl, tail;
        ld3(triple, is64, j, N, head, rl, tail);
        float h0 = inp[head * OUT_DIM + lane];
        float r0 = ldf(rel_embed, f32, (long)rl * OUT_DIM + lane);
        float t0 = inp[tail * OUT_DIM + lane];
        float h1 = __shfl_down(h0, 1, 64), h2 = __shfl_down(h0, 2, 64);
        float r1 = __shfl_down(r0, 1, 64), r2 = __shfl_down(r0, 2, 64);
        float t1 = __shfl_down(t0, 1, 64), t2 = __shfl_down(t0, 2, 64);

        float acc = 0.f;
        #pragma unroll
        for (int c = 0; c < NCH; ++c) {
            float y = A[c][0] * h0; y = fmaf(A[c][1], h1, y); y = fmaf(A[c][2], h2, y);
            y = fmaf(Bw[c][0], r0, y); y = fmaf(Bw[c][1], r1, y); y = fmaf(Bw[c][2], r2, y);
            y = fmaf(Cw[c][0], t0, y); y = fmaf(Cw[c][1], t1, y); y = fmaf(Cw[c][2], t2, y);
            y = fmaf(k1c[c], y, k0c[c]);
            y = fmaxf(y, 0.f);
            acc = fmaf(y, fcl[c], acc);
        }
        #pragma unroll
        for (int s = 32; s > 0; s >>= 1) acc += __shfl_xor(acc, s, 64);

        if (lane == 0) {
            float ev = acc > 0.f ? acc : 0.01f * acc;   // leaky_relu
            e_out[j] = ev;
            atomicMax(&mkey[head], f2key(ev));
        }
    }
}

// ---------------------------------------------------------------------------
// Kernel 3: e[j] <- exp(e[j] - m[head]) in place; denom[head] += ex
// ---------------------------------------------------------------------------
__global__ __launch_bounds__(256) void k_denom(
    float* __restrict__ e_buf, const void* __restrict__ triple,
    const int* __restrict__ flags,
    const unsigned int* __restrict__ mkey,
    float* __restrict__ denom, int E, int N)
{
    const bool is64 = flags[0] != 0;
    int j = blockIdx.x * blockDim.x + threadIdx.x;
    if (j >= E) return;
    int head, rl, tail;
    ld3(triple, is64, j, N, head, rl, tail);
    float m  = key2f(mkey[head]);
    float ex = __expf(fminf(e_buf[j] - m, 0.f));   // identity when correct; NaN firewall
    e_buf[j] = ex;
    atomicAdd(&denom[head], ex);
}

// ---------------------------------------------------------------------------
// Kernel 4: agg[head] += (ex/denom[head]) * inp[tail]   (wave per edge)
// ---------------------------------------------------------------------------
__global__ __launch_bounds__(256) void k_agg(
    const float* __restrict__ inp, const void* __restrict__ triple,
    const int* __restrict__ flags,
    const float* __restrict__ ex, const float* __restrict__ denom,
    float* __restrict__ agg, int E, int N)
{
    const bool is64  = flags[0] != 0;
    const int lane   = threadIdx.x & 63;
    const int wave   = (blockIdx.x * (blockDim.x >> 6)) + (threadIdx.x >> 6);
    const int nwaves = gridDim.x * (blockDim.x >> 6);
    for (int j = wave; j < E; j += nwaves) {
        int head, rl, tail;
        ld3(triple, is64, j, N, head, rl, tail);
        float a = ex[j] / denom[head];
        float v = a * inp[tail * OUT_DIM + lane];
        atomicAdd(&agg[head * OUT_DIM + lane], v);
    }
}

// ---------------------------------------------------------------------------
// Kernel 5: out = elu(agg + inp); store fp32 or bf16 per detected dtype
// ---------------------------------------------------------------------------
__global__ __launch_bounds__(256) void k_out(
    const float* __restrict__ inp, const float* __restrict__ agg,
    const int* __restrict__ flags, void* __restrict__ out, int total)
{
    const bool f32 = flags[1] != 0;
    int i = blockIdx.x * blockDim.x + threadIdx.x;
    if (i >= total) return;
    float x = agg[i] + inp[i];
    float y = x > 0.f ? x : expm1f(x);
    if (f32) ((float*)out)[i] = y;
    else     ((__hip_bfloat16*)out)[i] = __float2bfloat16(y);
}

// ---------------------------------------------------------------------------
extern "C" void kernel_launch(void* const* d_in, const int* in_sizes, int n_in,
                              void* d_out, int out_size, void* d_ws, size_t ws_size,
                              hipStream_t stream)
{
    const void* input     = d_in[0];
    const void* triple    = d_in[1];
    const void* W         = d_in[2];
    const void* rel_embed = d_in[3];
    const void* conv_w    = d_in[4];
    const void* conv_b    = d_in[5];
    const void* fc_w      = d_in[6];
    const void* bn1g      = d_in[7];
    const void* bn1b      = d_in[8];
    const void* bn2g      = d_in[9];
    const void* bn2b      = d_in[10];

    const int N = in_sizes[0] / IN_DIM;   // 50000
    const int E = in_sizes[1] / 3;        // 320000

    auto align = [](size_t x) { return (x + 255) & ~(size_t)255; };
    char* base = (char*)d_ws;
    size_t off = 0;
    int*   flags = (int*)(base + off);   off = align(off + 8);
    float* inp   = (float*)(base + off); off = align(off + (size_t)N * OUT_DIM * 4);
    float* e_buf = (float*)(base + off); off = align(off + (size_t)E * 4);
    size_t zero_off = off;
    unsigned int* mkey = (unsigned int*)(base + off); off = align(off + (size_t)N * 4);
    float* denom = (float*)(base + off); off = align(off + (size_t)N * 4);
    float* agg   = (float*)(base + off); off = align(off + (size_t)N * OUT_DIM * 4);
    size_t zero_bytes = off - zero_off;

    hipMemsetAsync(base + zero_off, 0, zero_bytes, stream);

    int probeT = E < 1024 ? E : 1024;
    k_detect<<<1, 256, 0, stream>>>(triple, probeT, N,
                                    (const unsigned int*)input, 1024, flags);
    k_gemm<<<(N + 3) / 4, 256, 0, stream>>>(input, W, flags, inp, N);
    k_score<<<1280, 256, 0, stream>>>(inp, triple, flags, rel_embed, conv_w, conv_b,
                                      fc_w, bn1g, bn1b, bn2g, bn2b, e_buf, mkey, E, N);
    k_denom<<<(E + 255) / 256, 256, 0, stream>>>(e_buf, triple, flags, mkey, denom, E, N);
    k_agg<<<2048, 256, 0, stream>>>(inp, triple, flags, e_buf, denom, agg, E, N);
    k_out<<<(N * OUT_DIM + 255) / 256, 256, 0, stream>>>(inp, agg, flags, d_out, N * OUT_DIM);
}

// Round 5
// 385.301 us; speedup vs baseline: 1.2063x; 1.2063x over previous
//
#include <hip/hip_runtime.h>
#include <hip/hip_bf16.h>
#include <stdint.h>

#define IN_DIM   128
#define OUT_DIM  64
#define NCH      8
#define N_REL    500
#define BN_EPS   1e-5f

// ---------------------------------------------------------------------------
// Wave-uniform dual-dtype float load: f32 ? fp32[i] : bf16[i]
// (dtype worlds verified R0-R4: floats are fp32, triple int32; probes kept
//  because they cost ~2 us and make the kernel dtype-proof.)
// ---------------------------------------------------------------------------
__device__ __forceinline__ float ldf(const void* p, bool f32, long i) {
    return f32 ? ((const float*)p)[i]
               : __bfloat162float(((const __hip_bfloat16*)p)[i]);
}

__global__ __launch_bounds__(256) void k_detect(
    const void* __restrict__ triple, int probeT, int N,
    const unsigned int* __restrict__ finput, int probeW,
    int* __restrict__ flags)
{
    __shared__ int bad64, bigexp;
    if (threadIdx.x == 0) { bad64 = 0; bigexp = 0; }
    __syncthreads();
    const int64_t* t64 = (const int64_t*)triple;
    int lb = 0;
    for (int j = threadIdx.x; j < probeT; j += 256) {
        int64_t h = t64[3 * j], r = t64[3 * j + 1], t = t64[3 * j + 2];
        if (h < 0 || h >= N || r < 0 || r >= N_REL || t < 0 || t >= N) lb = 1;
    }
    if (lb) atomicOr(&bad64, 1);
    int le = 0;
    for (int i = threadIdx.x; i < probeW; i += 256) {
        unsigned int e = (finput[i] >> 7) & 0xFF;
        if (e >= 134) le = 1;
    }
    if (le) atomicOr(&bigexp, 1);
    __syncthreads();
    if (threadIdx.x == 0) {
        flags[0] = (bad64 == 0) ? 1 : 0;   // int64 triple
        flags[1] = bigexp ? 1 : 0;         // fp32 floats
    }
}

__device__ __forceinline__ void ld3(const void* tp, bool is64, int j, int N,
                                    int& h, int& r, int& t)
{
    if (is64) {
        const int64_t* p = (const int64_t*)tp;
        h = (int)p[3 * j]; r = (int)p[3 * j + 1]; t = (int)p[3 * j + 2];
    } else {
        const int* p = (const int*)tp;
        h = p[3 * j]; r = p[3 * j + 1]; t = p[3 * j + 2];
    }
    h = min(max(h, 0), N - 1);
    r = min(max(r, 0), N_REL - 1);
    t = min(max(t, 0), N - 1);
}

// ---------------------------------------------------------------------------
// Kernel 1: inp = input @ W. 64 rows/block, W (32KB) + X (32KB) in LDS.
// Wave w computes rows w*16..w*16+15; lane = output col. W staged ONCE per
// 64 rows (16x less W traffic than R4's 4 rows/block).
// ---------------------------------------------------------------------------
__global__ __launch_bounds__(256) void k_gemm(
    const void* __restrict__ X, const void* __restrict__ W,
    const int* __restrict__ flags, float* __restrict__ out, int N)
{
    const bool f32 = flags[1] != 0;
    __shared__ float Wl[IN_DIM * OUT_DIM];   // 32 KB
    __shared__ float Xl[64 * IN_DIM];        // 32 KB (reads are broadcast; no pad needed)
    const int rows0 = blockIdx.x * 64;

    if (f32) {
        const float4* W4 = (const float4*)W;
        for (int i = threadIdx.x; i < IN_DIM * OUT_DIM / 4; i += 256)
            ((float4*)Wl)[i] = W4[i];
        for (int i = threadIdx.x; i < 64 * IN_DIM / 4; i += 256) {
            int r = i >> 5, k4 = i & 31;
            int rr = rows0 + r;
            float4 v = make_float4(0.f, 0.f, 0.f, 0.f);
            if (rr < N) v = ((const float4*)X)[(long)rr * (IN_DIM / 4) + k4];
            ((float4*)Xl)[i] = v;
        }
    } else {
        for (int i = threadIdx.x; i < IN_DIM * OUT_DIM; i += 256)
            Wl[i] = ldf(W, false, i);
        for (int i = threadIdx.x; i < 64 * IN_DIM; i += 256) {
            int r = i >> 7, k = i & (IN_DIM - 1);
            int rr = rows0 + r;
            Xl[i] = (rr < N) ? ldf(X, false, (long)rr * IN_DIM + k) : 0.f;
        }
    }
    __syncthreads();

    const int w = threadIdx.x >> 6;
    const int c = threadIdx.x & 63;
    float acc[16];
    #pragma unroll
    for (int r = 0; r < 16; ++r) acc[r] = 0.f;

    for (int k4 = 0; k4 < IN_DIM / 4; ++k4) {
        int k = k4 * 4;
        float w0 = Wl[(k + 0) * OUT_DIM + c];
        float w1 = Wl[(k + 1) * OUT_DIM + c];
        float w2 = Wl[(k + 2) * OUT_DIM + c];
        float w3 = Wl[(k + 3) * OUT_DIM + c];
        #pragma unroll
        for (int r = 0; r < 16; ++r) {
            const float4 x = *(const float4*)&Xl[(w * 16 + r) * IN_DIM + k]; // broadcast
            acc[r] = fmaf(x.w, w3, fmaf(x.z, w2, fmaf(x.y, w1, fmaf(x.x, w0, acc[r]))));
        }
    }
    #pragma unroll
    for (int r = 0; r < 16; ++r) {
        int rr = rows0 + w * 16 + r;
        if (rr < N) out[(long)rr * OUT_DIM + c] = acc[r];
    }
}

// ---------------------------------------------------------------------------
// Kernel 2: per-edge score -> e[j] only (no atomics). One wave per TWO
// adjacent edges per iteration: two independent gather chains in flight.
// ---------------------------------------------------------------------------
__global__ __launch_bounds__(256) void k_score(
    const float* __restrict__ inp, const void* __restrict__ triple,
    const int* __restrict__ flags,
    const void* __restrict__ rel_embed,
    const void* __restrict__ conv_w, const void* __restrict__ conv_b,
    const void* __restrict__ fc_w,
    const void* __restrict__ bn1g, const void* __restrict__ bn1b,
    const void* __restrict__ bn2g, const void* __restrict__ bn2b,
    float* __restrict__ e_out, int E, int N)
{
    const bool is64  = flags[0] != 0;
    const bool f32   = flags[1] != 0;
    const int lane   = threadIdx.x & 63;
    const int wave   = (blockIdx.x * (blockDim.x >> 6)) + (threadIdx.x >> 6);
    const int nwaves = gridDim.x * (blockDim.x >> 6);

    const float rs  = rsqrtf(1.f + BN_EPS);
    const float s1  = ldf(bn1g, f32, 0) * rs;
    const float be1 = ldf(bn1b, f32, 0);

    // Fold BN1*BN2 scale directly into stencil weights; biases into k0c.
    float A[NCH][3], Bw[NCH][3], Cw[NCH][3], k0c[NCH], fcl[NCH];
    #pragma unroll
    for (int c = 0; c < NCH; ++c) {
        float s2 = ldf(bn2g, f32, c) * rs;
        float k1 = s1 * s2;
        float wsum = 0.f;
        #pragma unroll
        for (int dh = 0; dh < 3; ++dh) {
            float a  = ldf(conv_w, f32, c * 9 + dh * 3 + 0);
            float b  = ldf(conv_w, f32, c * 9 + dh * 3 + 1);
            float cc = ldf(conv_w, f32, c * 9 + dh * 3 + 2);
            wsum += a + b + cc;
            A[c][dh] = k1 * a; Bw[c][dh] = k1 * b; Cw[c][dh] = k1 * cc;
        }
        float b2 = ldf(bn2b, f32, c);
        k0c[c] = (be1 * wsum + ldf(conv_b, f32, c)) * s2 + b2;
        fcl[c] = (lane < 62) ? ldf(fc_w, f32, c * 62 + lane) : 0.f;
    }

    for (int j0 = 2 * wave; j0 < E; j0 += 2 * nwaves) {
        const int j1 = j0 + 1;
        const bool has1 = j1 < E;
        int ha, ra, ta, hb, rb, tb;
        ld3(triple, is64, j0, N, ha, ra, ta);
        ld3(triple, is64, has1 ? j1 : j0, N, hb, rb, tb);

        float h0a = inp[(long)ha * OUT_DIM + lane];
        float r0a = ldf(rel_embed, f32, (long)ra * OUT_DIM + lane);
        float t0a = inp[(long)ta * OUT_DIM + lane];
        float h0b = inp[(long)hb * OUT_DIM + lane];
        float r0b = ldf(rel_embed, f32, (long)rb * OUT_DIM + lane);
        float t0b = inp[(long)tb * OUT_DIM + lane];

        float h1a = __shfl_down(h0a, 1, 64), h2a = __shfl_down(h0a, 2, 64);
        float r1a = __shfl_down(r0a, 1, 64), r2a = __shfl_down(r0a, 2, 64);
        float t1a = __shfl_down(t0a, 1, 64), t2a = __shfl_down(t0a, 2, 64);
        float h1b = __shfl_down(h0b, 1, 64), h2b = __shfl_down(h0b, 2, 64);
        float r1b = __shfl_down(r0b, 1, 64), r2b = __shfl_down(r0b, 2, 64);
        float t1b = __shfl_down(t0b, 1, 64), t2b = __shfl_down(t0b, 2, 64);

        float acca = 0.f, accb = 0.f;
        #pragma unroll
        for (int c = 0; c < NCH; ++c) {
            float ya = k0c[c];
            ya = fmaf(A[c][0], h0a, ya); ya = fmaf(A[c][1], h1a, ya); ya = fmaf(A[c][2], h2a, ya);
            ya = fmaf(Bw[c][0], r0a, ya); ya = fmaf(Bw[c][1], r1a, ya); ya = fmaf(Bw[c][2], r2a, ya);
            ya = fmaf(Cw[c][0], t0a, ya); ya = fmaf(Cw[c][1], t1a, ya); ya = fmaf(Cw[c][2], t2a, ya);
            acca = fmaf(fmaxf(ya, 0.f), fcl[c], acca);
            float yb = k0c[c];
            yb = fmaf(A[c][0], h0b, yb); yb = fmaf(A[c][1], h1b, yb); yb = fmaf(A[c][2], h2b, yb);
            yb = fmaf(Bw[c][0], r0b, yb); yb = fmaf(Bw[c][1], r1b, yb); yb = fmaf(Bw[c][2], r2b, yb);
            yb = fmaf(Cw[c][0], t0b, yb); yb = fmaf(Cw[c][1], t1b, yb); yb = fmaf(Cw[c][2], t2b, yb);
            accb = fmaf(fmaxf(yb, 0.f), fcl[c], accb);
        }
        #pragma unroll
        for (int s = 32; s > 0; s >>= 1) {
            acca += __shfl_xor(acca, s, 64);
            accb += __shfl_xor(accb, s, 64);
        }
        if (lane == 0) {
            e_out[j0] = acca > 0.f ? acca : 0.01f * acca;
            if (has1) e_out[j1] = accb > 0.f ? accb : 0.01f * accb;
        }
    }
}

// ---------------------------------------------------------------------------
// CSR build: count -> scan -> copy -> scatter
// ---------------------------------------------------------------------------
__global__ __launch_bounds__(256) void k_count(
    const void* __restrict__ triple, const int* __restrict__ flags,
    int* __restrict__ cnt, int E, int N)
{
    int j = blockIdx.x * blockDim.x + threadIdx.x;
    if (j >= E) return;
    int h, r, t; ld3(triple, flags[0] != 0, j, N, h, r, t);
    atomicAdd(&cnt[h], 1);
}

__global__ __launch_bounds__(1024) void k_scan(
    const int* __restrict__ cnt, int* __restrict__ off, int N)
{
    __shared__ int part[1024];
    const int t = threadIdx.x;
    const int C = (N + 1023) / 1024;
    const int lo = t * C, hi = min(lo + C, N);
    int s = 0;
    for (int i = lo; i < hi; ++i) s += cnt[i];
    part[t] = s;
    __syncthreads();
    for (int d = 1; d < 1024; d <<= 1) {
        int v = (t >= d) ? part[t - d] : 0;
        __syncthreads();
        part[t] += v;
        __syncthreads();
    }
    int run = part[t] - s;            // exclusive prefix of this chunk
    if (t == 0) off[0] = 0;
    for (int i = lo; i < hi; ++i) {
        run += cnt[i];
        off[i + 1] = run;
    }
}

__global__ __launch_bounds__(256) void k_copyoff(
    const int* __restrict__ off, int* __restrict__ woff, int N)
{
    int i = blockIdx.x * blockDim.x + threadIdx.x;
    if (i < N) woff[i] = off[i];
}

__global__ __launch_bounds__(256) void k_scatter(
    const void* __restrict__ triple, const int* __restrict__ flags,
    int* __restrict__ woff, int* __restrict__ eid, int E, int N)
{
    int j = blockIdx.x * blockDim.x + threadIdx.x;
    if (j >= E) return;
    int h, r, t; ld3(triple, flags[0] != 0, j, N, h, r, t);
    int pos = atomicAdd(&woff[h], 1);
    eid[pos] = j;
}

// ---------------------------------------------------------------------------
// Kernel 3: fused per-head softmax + aggregation + elu + store.
// One wave per head; zero atomics; agg lives in one register per lane.
// ---------------------------------------------------------------------------
__global__ __launch_bounds__(256) void k_fused(
    const float* __restrict__ inp, const void* __restrict__ triple,
    const int* __restrict__ flags, const float* __restrict__ e,
    const int* __restrict__ off, const int* __restrict__ eid,
    void* __restrict__ out, int N)
{
    const bool is64 = flags[0] != 0;
    const bool f32  = flags[1] != 0;
    const int lane   = threadIdx.x & 63;
    const int wave   = (blockIdx.x * (blockDim.x >> 6)) + (threadIdx.x >> 6);
    const int nwaves = gridDim.x * (blockDim.x >> 6);

    for (int h = wave; h < N; h += nwaves) {
        const int d0 = off[h], d1 = off[h + 1];
        const int deg = d1 - d0;
        float agg = 0.f;
        if (deg > 0 && deg <= 64) {
            // fast path: lane k owns edge k; e/tail stay in registers
            float ev = -INFINITY; int tl = 0;
            if (lane < deg) {
                int id = eid[d0 + lane];
                ev = e[id];
                int hh, rr, tt; ld3(triple, is64, id, N, hh, rr, tt);
                tl = tt;
            }
            float m = ev;
            #pragma unroll
            for (int s = 32; s > 0; s >>= 1) m = fmaxf(m, __shfl_xor(m, s, 64));
            float ex = (lane < deg) ? __expf(ev - m) : 0.f;
            float ssum = ex;
            #pragma unroll
            for (int s = 32; s > 0; s >>= 1) ssum += __shfl_xor(ssum, s, 64);
            float inv = 1.f / ssum;
            for (int k = 0; k < deg; ++k) {
                float wk = __shfl(ex, k, 64) * inv;
                int   tk = __shfl(tl, k, 64);
                agg = fmaf(wk, inp[(long)tk * OUT_DIM + lane], agg);
            }
        } else if (deg > 64) {
            float m = -INFINITY;
            for (int b = 0; b < deg; b += 64) {
                float v = -INFINITY;
                if (b + lane < deg) v = e[eid[d0 + b + lane]];
                #pragma unroll
                for (int s = 32; s > 0; s >>= 1) v = fmaxf(v, __shfl_xor(v, s, 64));
                m = fmaxf(m, v);
            }
            float ssum = 0.f;
            for (int b = 0; b < deg; b += 64) {
                float v = 0.f;
                if (b + lane < deg) v = __expf(e[eid[d0 + b + lane]] - m);
                #pragma unroll
                for (int s = 32; s > 0; s >>= 1) v += __shfl_xor(v, s, 64);
                ssum += v;
            }
            float inv = 1.f / ssum;
            for (int b = 0; b < deg; b += 64) {
                float ex = 0.f; int tl = 0;
                if (b + lane < deg) {
                    int id = eid[d0 + b + lane];
                    ex = __expf(e[id] - m);
                    int hh, rr, tt; ld3(triple, is64, id, N, hh, rr, tt);
                    tl = tt;
                }
                int cmax = min(deg - b, 64);
                for (int k = 0; k < cmax; ++k) {
                    float wk = __shfl(ex, k, 64) * inv;
                    int   tk = __shfl(tl, k, 64);
                    agg = fmaf(wk, inp[(long)tk * OUT_DIM + lane], agg);
                }
            }
        }
        float x = agg + inp[(long)h * OUT_DIM + lane];
        float y = x > 0.f ? x : expm1f(x);
        if (f32) ((float*)out)[(long)h * OUT_DIM + lane] = y;
        else     ((__hip_bfloat16*)out)[(long)h * OUT_DIM + lane] = __float2bfloat16(y);
    }
}

// ---------------------------------------------------------------------------
extern "C" void kernel_launch(void* const* d_in, const int* in_sizes, int n_in,
                              void* d_out, int out_size, void* d_ws, size_t ws_size,
                              hipStream_t stream)
{
    const void* input     = d_in[0];
    const void* triple    = d_in[1];
    const void* W         = d_in[2];
    const void* rel_embed = d_in[3];
    const void* conv_w    = d_in[4];
    const void* conv_b    = d_in[5];
    const void* fc_w      = d_in[6];
    const void* bn1g      = d_in[7];
    const void* bn1b      = d_in[8];
    const void* bn2g      = d_in[9];
    const void* bn2b      = d_in[10];

    const int N = in_sizes[0] / IN_DIM;   // 50000
    const int E = in_sizes[1] / 3;        // 320000

    auto align = [](size_t x) { return (x + 255) & ~(size_t)255; };
    char* base = (char*)d_ws;
    size_t off_b = 0;
    int*   flags = (int*)(base + off_b);   off_b = align(off_b + 8);
    float* inp   = (float*)(base + off_b); off_b = align(off_b + (size_t)N * OUT_DIM * 4);
    float* e_buf = (float*)(base + off_b); off_b = align(off_b + (size_t)E * 4);
    int*   eid   = (int*)(base + off_b);   off_b = align(off_b + (size_t)E * 4);
    int*   offs  = (int*)(base + off_b);   off_b = align(off_b + (size_t)(N + 1) * 4);
    int*   woff  = (int*)(base + off_b);   off_b = align(off_b + (size_t)N * 4);
    size_t zero_off = off_b;
    int*   cnt   = (int*)(base + off_b);   off_b = align(off_b + (size_t)N * 4);
    size_t zero_bytes = off_b - zero_off;

    hipMemsetAsync(base + zero_off, 0, zero_bytes, stream);

    int probeT = E < 1024 ? E : 1024;
    k_detect<<<1, 256, 0, stream>>>(triple, probeT, N,
                                    (const unsigned int*)input, 1024, flags);
    k_count<<<(E + 255) / 256, 256, 0, stream>>>(triple, flags, cnt, E, N);
    k_scan<<<1, 1024, 0, stream>>>(cnt, offs, N);
    k_copyoff<<<(N + 255) / 256, 256, 0, stream>>>(offs, woff, N);
    k_scatter<<<(E + 255) / 256, 256, 0, stream>>>(triple, flags, woff, eid, E, N);
    k_gemm<<<(N + 63) / 64, 256, 0, stream>>>(input, W, flags, inp, N);
    k_score<<<4096, 256, 0, stream>>>(inp, triple, flags, rel_embed, conv_w, conv_b,
                                      fc_w, bn1g, bn1b, bn2g, bn2b, e_buf, E, N);
    k_fused<<<3125, 256, 0, stream>>>(inp, triple, flags, e_buf, offs, eid, d_out, N);
}